// Round 4
// baseline (216.895 us; speedup 1.0000x reference)
//
#include <hip/hip_runtime.h>
#include <hip/hip_bf16.h>

#define SIZE 6144
#define DDIM 2048
#define BHALF 2048
#define BIJ 4096
#define NT 48   // 6144 / 128 tiles per dim

typedef __attribute__((ext_vector_type(8))) short bf16x8;
typedef __attribute__((ext_vector_type(4))) float f32x4;
typedef __attribute__((ext_vector_type(4))) unsigned int u32x4;

__device__ __forceinline__ float block_reduce_sum(float v, float* red) {
    #pragma unroll
    for (int off = 32; off; off >>= 1) v += __shfl_xor(v, off, 64);
    int lane = threadIdx.x & 63, wid = threadIdx.x >> 6;
    if (lane == 0) red[wid] = v;
    __syncthreads();
    float t = red[0] + red[1] + red[2] + red[3];
    __syncthreads();
    return t;
}

// One block (256 thr) per row: L2-normalize in fp32, write bf16 z, and
// dii[r] = ||z_bf16[r]||^2 (fp32) so the diagonal exp term cancels
// consistently with the MFMA-computed sim[i,i].
__global__ __launch_bounds__(256) void normalize_kernel(
    const float* __restrict__ ei, const float* __restrict__ ej,
    const float* __restrict__ ek,
    unsigned short* __restrict__ zb, float* __restrict__ dii)
{
    __shared__ float red[4];
    int r = blockIdx.x;
    const float* src = (r < BHALF)   ? (ei + (size_t)r * DDIM)
                     : (r < 2*BHALF) ? (ej + (size_t)(r - BHALF) * DDIM)
                                     : (ek + (size_t)(r - 2*BHALF) * DDIM);
    int t = threadIdx.x;
    float4 v0 = ((const float4*)src)[t*2];
    float4 v1 = ((const float4*)src)[t*2 + 1];
    float ss = v0.x*v0.x + v0.y*v0.y + v0.z*v0.z + v0.w*v0.w
             + v1.x*v1.x + v1.y*v1.y + v1.z*v1.z + v1.w*v1.w;
    float tot = block_reduce_sum(ss, red);
    float scale = 1.0f / fmaxf(sqrtf(tot), 1e-12f);

    float xs[8] = {v0.x, v0.y, v0.z, v0.w, v1.x, v1.y, v1.z, v1.w};
    unsigned short u[8];
    float d = 0.f;
    #pragma unroll
    for (int j = 0; j < 8; ++j) {
        __hip_bfloat16 h = __float2bfloat16(xs[j] * scale);
        u[j] = *(unsigned short*)&h;
        float f = __bfloat162float(h);
        d += f * f;
    }
    *(u32x4*)&zb[(size_t)r * DDIM + t*8] = *(u32x4*)u;
    float dtot = block_reduce_sum(d, red);
    if (t == 0) dii[r] = dtot;
}

// Pipelined symmetric sim: upper-triangular 128x128 tiles (rt <= ct).
// Fragment-linear LDS (conflict-free ds_read_b128), dbuf, 2 phases/K-tile,
// counted vmcnt(4), raw barriers, setprio around MFMA cluster.
__global__ __launch_bounds__(256) void simexp_kernel(
    const unsigned short* __restrict__ zb, float* __restrict__ S)
{
    // [buf][ksub s][frag 0..7][512 shorts = 64 lanes x 8 bf16]
    __shared__ short As[2][2][8][512];
    __shared__ short Bs[2][2][8][512];

    // triangular decode: bid -> (rt, ct), ct >= rt
    int rem = blockIdx.x;
    int rt = 0, width = NT;
    while (rem >= width) { rem -= width; ++rt; --width; }
    const int ct = rt + rem;

    const int tid  = threadIdx.x;
    const int lane = tid & 63;
    const int w    = tid >> 6;       // wave 0..3
    const int wr   = w >> 1, wc = w & 1;
    const int rowA0 = rt * 128, colB0 = ct * 128;
    const int l15 = lane & 15, l4 = lane >> 4;

    // staging duties: wave w stages A-frags {2w,2w+1} and B-frags {2w,2w+1}
    // global element offset for lane's 16B chunk of each frag row
    const size_t aR0 = (size_t)(rowA0 + (2*w)*16 + l15) * DDIM + l4*8;
    const size_t aR1 = aR0 + (size_t)16 * DDIM;
    const size_t bR0 = (size_t)(colB0 + (2*w)*16 + l15) * DDIM + l4*8;
    const size_t bR1 = bR0 + (size_t)16 * DDIM;

#define GLDS(gofs, larr, buf, s, fm)                                         \
    __builtin_amdgcn_global_load_lds(                                        \
        (const __attribute__((address_space(1))) void*)(zb + (gofs)),        \
        (__attribute__((address_space(3))) void*)&larr[buf][s][fm][0],       \
        16, 0, 0)

#define STAGE(buf, kk, s) do {                                               \
    GLDS(aR0 + (kk) + (s)*32, As, buf, s, 2*w);                              \
    GLDS(aR1 + (kk) + (s)*32, As, buf, s, 2*w + 1);                          \
    GLDS(bR0 + (kk) + (s)*32, Bs, buf, s, 2*w);                              \
    GLDS(bR1 + (kk) + (s)*32, Bs, buf, s, 2*w + 1);                          \
} while (0)

    f32x4 acc[4][4];
    #pragma unroll
    for (int mi = 0; mi < 4; ++mi)
        #pragma unroll
        for (int ni = 0; ni < 4; ++ni)
            acc[mi][ni] = (f32x4){0.f, 0.f, 0.f, 0.f};

    // prologue: stage tile 0 (both ksub chunks) into buf 0
    STAGE(0, 0, 0);
    STAGE(0, 0, 1);
    asm volatile("s_waitcnt vmcnt(0)" ::: "memory");
    __builtin_amdgcn_s_barrier();

#define MFMA_CLUSTER(af, bq)                                                 \
    __builtin_amdgcn_s_setprio(1);                                           \
    _Pragma("unroll")                                                        \
    for (int mi = 0; mi < 4; ++mi)                                           \
        _Pragma("unroll")                                                    \
        for (int ni = 0; ni < 4; ++ni)                                       \
            acc[mi][ni] = __builtin_amdgcn_mfma_f32_16x16x32_bf16(           \
                af[mi], bq[ni], acc[mi][ni], 0, 0, 0);                       \
    __builtin_amdgcn_s_setprio(0);

    for (int t = 0; t < 31; ++t) {
        const int cur = t & 1, nxt = cur ^ 1;
        const size_t kkn = (size_t)(t + 1) * 64;
        // ---- phase 0 (ksub 0)
        {
            bf16x8 af[4], bq[4];
            #pragma unroll
            for (int mi = 0; mi < 4; ++mi)
                af[mi] = *(const bf16x8*)&As[cur][0][wr*4 + mi][lane*8];
            #pragma unroll
            for (int ni = 0; ni < 4; ++ni)
                bq[ni] = *(const bf16x8*)&Bs[cur][0][wc*4 + ni][lane*8];
            STAGE(nxt, kkn, 0);
            asm volatile("s_waitcnt vmcnt(4)" ::: "memory");
            __builtin_amdgcn_s_barrier();
            MFMA_CLUSTER(af, bq);
        }
        // ---- phase 1 (ksub 1)
        {
            bf16x8 af[4], bq[4];
            #pragma unroll
            for (int mi = 0; mi < 4; ++mi)
                af[mi] = *(const bf16x8*)&As[cur][1][wr*4 + mi][lane*8];
            #pragma unroll
            for (int ni = 0; ni < 4; ++ni)
                bq[ni] = *(const bf16x8*)&Bs[cur][1][wc*4 + ni][lane*8];
            STAGE(nxt, kkn, 1);
            asm volatile("s_waitcnt vmcnt(4)" ::: "memory");
            __builtin_amdgcn_s_barrier();
            MFMA_CLUSTER(af, bq);
        }
    }
    // drain: last K-tile (buf 1), compute-only
    asm volatile("s_waitcnt vmcnt(0)" ::: "memory");
    __builtin_amdgcn_s_barrier();
    #pragma unroll
    for (int s = 0; s < 2; ++s) {
        bf16x8 af[4], bq[4];
        #pragma unroll
        for (int mi = 0; mi < 4; ++mi)
            af[mi] = *(const bf16x8*)&As[1][s][wr*4 + mi][lane*8];
        #pragma unroll
        for (int ni = 0; ni < 4; ++ni)
            bq[ni] = *(const bf16x8*)&Bs[1][s][wc*4 + ni][lane*8];
        MFMA_CLUSTER(af, bq);
    }

    // exp in-register (reused for both row- and col-sums)
    #pragma unroll
    for (int mi = 0; mi < 4; ++mi)
        #pragma unroll
        for (int ni = 0; ni < 4; ++ni)
            #pragma unroll
            for (int q = 0; q < 4; ++q)
                acc[mi][ni][q] = __expf(10.0f * acc[mi][ni][q]);

    // ---- row-sums: C/D row = (lane>>4)*4 + q (+mi*16), col = lane&15 (+ni*16)
    {
        float rs[4][4];
        #pragma unroll
        for (int mi = 0; mi < 4; ++mi)
            #pragma unroll
            for (int q = 0; q < 4; ++q) {
                float s = 0.f;
                #pragma unroll
                for (int ni = 0; ni < 4; ++ni) s += acc[mi][ni][q];
                rs[mi][q] = s;
            }
        #pragma unroll
        for (int off = 1; off < 16; off <<= 1)
            #pragma unroll
            for (int mi = 0; mi < 4; ++mi)
                #pragma unroll
                for (int q = 0; q < 4; ++q)
                    rs[mi][q] += __shfl_xor(rs[mi][q], off, 64);

        if ((lane & 15) == 0) {
            float* St = S + ((ct < BIJ / 128) ? 0 : SIZE);
            int rq = (lane >> 4) * 4;
            #pragma unroll
            for (int mi = 0; mi < 4; ++mi)
                #pragma unroll
                for (int q = 0; q < 4; ++q)
                    atomicAdd(&St[rowA0 + wr*64 + mi*16 + rq + q], rs[mi][q]);
        }
    }

    // ---- col-sums (transpose contribution), off-diagonal tiles only
    if (rt != ct) {
        float cs[4];
        #pragma unroll
        for (int ni = 0; ni < 4; ++ni) {
            float s = 0.f;
            #pragma unroll
            for (int mi = 0; mi < 4; ++mi)
                #pragma unroll
                for (int q = 0; q < 4; ++q) s += acc[mi][ni][q];
            cs[ni] = s;
        }
        #pragma unroll
        for (int off = 16; off < 64; off <<= 1)
            #pragma unroll
            for (int ni = 0; ni < 4; ++ni)
                cs[ni] += __shfl_xor(cs[ni], off, 64);

        if (lane < 16) {
            float* St = S + ((rt < BIJ / 128) ? 0 : SIZE);
            #pragma unroll
            for (int ni = 0; ni < 4; ++ni)
                atomicAdd(&St[colB0 + wc*64 + ni*16 + lane], cs[ni]);
        }
    }
}

__global__ void zero_kernel(float* __restrict__ p, int n) {
    int i = blockIdx.x * 256 + threadIdx.x;
    if (i < n) p[i] = 0.f;
}

// Single block: per-row loss terms, total, write scalar.
__global__ __launch_bounds__(256) void loss_kernel(
    const float* __restrict__ S, const float* __restrict__ dii,
    float* __restrict__ out)
{
    __shared__ float red[4];
    float local = 0.f;
    const float c1 = logf((float)(BIJ - 1));
    const float c2 = logf((float)(BHALF - 1));
    for (int r = threadIdx.x; r < SIZE; r += 256) {
        float s1 = S[r], s2 = S[SIZE + r];
        float eii = __expf(10.0f * dii[r]);
        float denom = s1 + s2 - eii;
        float num, c;
        if (r < BIJ) { num = s1 - eii; c = c1; }
        else         { num = s2 - eii; c = c2; }
        local += logf(denom) - logf(num) + c;
    }
    float tot = block_reduce_sum(local, red);
    if (threadIdx.x == 0) out[0] = tot / (float)SIZE;
}

extern "C" void kernel_launch(void* const* d_in, const int* in_sizes, int n_in,
                              void* d_out, int out_size, void* d_ws, size_t ws_size,
                              hipStream_t stream) {
    const float* ei = (const float*)d_in[0];
    const float* ej = (const float*)d_in[1];
    const float* ek = (const float*)d_in[2];
    float* out = (float*)d_out;

    char* ws = (char*)d_ws;
    unsigned short* zb = (unsigned short*)ws;                    // 6144*2048*2 = 25165824 B
    float* dii = (float*)(ws + 25165824);                        // 24576 B
    float* S   = (float*)(ws + 25165824 + 24576);                // 2*6144*4 = 49152 B

    zero_kernel<<<dim3(48), dim3(256), 0, stream>>>(S, 2 * SIZE);
    normalize_kernel<<<dim3(SIZE), dim3(256), 0, stream>>>(ei, ej, ek, zb, dii);
    simexp_kernel<<<dim3(NT * (NT + 1) / 2), dim3(256), 0, stream>>>(zb, S);
    loss_kernel<<<dim3(1), dim3(256), 0, stream>>>(S, dii, out);
}

// Round 5
// 215.754 us; speedup vs baseline: 1.0053x; 1.0053x over previous
//
#include <hip/hip_runtime.h>
#include <hip/hip_bf16.h>

#define SIZE 6144
#define DDIM 2048
#define BHALF 2048
#define BIJ 4096
#define NT 48   // 6144 / 128 tiles per dim

typedef __attribute__((ext_vector_type(8))) short bf16x8;
typedef __attribute__((ext_vector_type(4))) float f32x4;
typedef __attribute__((ext_vector_type(4))) unsigned int u32x4;

__device__ __forceinline__ float block_reduce_sum(float v, float* red) {
    #pragma unroll
    for (int off = 32; off; off >>= 1) v += __shfl_xor(v, off, 64);
    int lane = threadIdx.x & 63, wid = threadIdx.x >> 6;
    if (lane == 0) red[wid] = v;
    __syncthreads();
    float t = red[0] + red[1] + red[2] + red[3];
    __syncthreads();
    return t;
}

// One block (256 thr) per row: L2-normalize in fp32, write bf16 z, and
// dii[r] = ||z_bf16[r]||^2 (fp32) so the diagonal exp term cancels
// consistently with the MFMA-computed sim[i,i].
__global__ __launch_bounds__(256) void normalize_kernel(
    const float* __restrict__ ei, const float* __restrict__ ej,
    const float* __restrict__ ek,
    unsigned short* __restrict__ zb, float* __restrict__ dii)
{
    __shared__ float red[4];
    int r = blockIdx.x;
    const float* src = (r < BHALF)   ? (ei + (size_t)r * DDIM)
                     : (r < 2*BHALF) ? (ej + (size_t)(r - BHALF) * DDIM)
                                     : (ek + (size_t)(r - 2*BHALF) * DDIM);
    int t = threadIdx.x;
    float4 v0 = ((const float4*)src)[t*2];
    float4 v1 = ((const float4*)src)[t*2 + 1];
    float ss = v0.x*v0.x + v0.y*v0.y + v0.z*v0.z + v0.w*v0.w
             + v1.x*v1.x + v1.y*v1.y + v1.z*v1.z + v1.w*v1.w;
    float tot = block_reduce_sum(ss, red);
    float scale = 1.0f / fmaxf(sqrtf(tot), 1e-12f);

    float xs[8] = {v0.x, v0.y, v0.z, v0.w, v1.x, v1.y, v1.z, v1.w};
    unsigned short u[8];
    float d = 0.f;
    #pragma unroll
    for (int j = 0; j < 8; ++j) {
        __hip_bfloat16 h = __float2bfloat16(xs[j] * scale);
        u[j] = *(unsigned short*)&h;
        float f = __bfloat162float(h);
        d += f * f;
    }
    *(u32x4*)&zb[(size_t)r * DDIM + t*8] = *(u32x4*)u;
    float dtot = block_reduce_sum(d, red);
    if (t == 0) dii[r] = dtot;
}

// Symmetric sim, upper-triangular 128x128 tiles (rt <= ct).
// Round-2 schedule (full-tile stage + __syncthreads, compiler waits,
// ~5 blocks/CU TLP) + fragment-linear LDS (zero-conflict ds_read_b128).
// LDS layout: [ksub s][frag f][lane*8 bf16]; chunk (s,f) holds
// row = f*16 + (lane&15), k = s*32 + (lane>>4)*8 .. +7 — staged by
// per-lane global addressing, read back as 64x16B linear ds_read_b128.
__global__ __launch_bounds__(256) void simexp_kernel(
    const unsigned short* __restrict__ zb, float* __restrict__ S)
{
    __shared__ short As[2][8][512];   // 16 KiB
    __shared__ short Bs[2][8][512];   // 16 KiB

    // triangular decode: bid -> (rt, ct), ct >= rt
    int rem = blockIdx.x;
    int rt = 0, width = NT;
    while (rem >= width) { rem -= width; ++rt; --width; }
    const int ct = rt + rem;

    const int tid  = threadIdx.x;
    const int lane = tid & 63;
    const int w    = tid >> 6;       // wave 0..3
    const int wr   = w >> 1, wc = w & 1;
    const int rowA0 = rt * 128, colB0 = ct * 128;
    const int l15 = lane & 15, l4 = lane >> 4;

    // staging duties: wave w stages A-frags {2w,2w+1}, B-frags {2w,2w+1}
    const size_t aR0 = (size_t)(rowA0 + (2*w)*16 + l15) * DDIM + l4*8;
    const size_t aR1 = aR0 + (size_t)16 * DDIM;
    const size_t bR0 = (size_t)(colB0 + (2*w)*16 + l15) * DDIM + l4*8;
    const size_t bR1 = bR0 + (size_t)16 * DDIM;

#define GLDS(gofs, larr, s, fm)                                              \
    __builtin_amdgcn_global_load_lds(                                        \
        (const __attribute__((address_space(1))) void*)(zb + (gofs)),        \
        (__attribute__((address_space(3))) void*)&larr[s][fm][0],            \
        16, 0, 0)

    f32x4 acc[4][4];
    #pragma unroll
    for (int mi = 0; mi < 4; ++mi)
        #pragma unroll
        for (int ni = 0; ni < 4; ++ni)
            acc[mi][ni] = (f32x4){0.f, 0.f, 0.f, 0.f};

    for (int kt = 0; kt < DDIM; kt += 64) {
        __syncthreads();
        #pragma unroll
        for (int s = 0; s < 2; ++s) {
            GLDS(aR0 + kt + s*32, As, s, 2*w);
            GLDS(aR1 + kt + s*32, As, s, 2*w + 1);
            GLDS(bR0 + kt + s*32, Bs, s, 2*w);
            GLDS(bR1 + kt + s*32, Bs, s, 2*w + 1);
        }
        __syncthreads();
        #pragma unroll
        for (int s = 0; s < 2; ++s) {
            bf16x8 af[4], bq[4];
            #pragma unroll
            for (int mi = 0; mi < 4; ++mi)
                af[mi] = *(const bf16x8*)&As[s][wr*4 + mi][lane*8];
            #pragma unroll
            for (int ni = 0; ni < 4; ++ni)
                bq[ni] = *(const bf16x8*)&Bs[s][wc*4 + ni][lane*8];
            #pragma unroll
            for (int mi = 0; mi < 4; ++mi)
                #pragma unroll
                for (int ni = 0; ni < 4; ++ni)
                    acc[mi][ni] = __builtin_amdgcn_mfma_f32_16x16x32_bf16(
                        af[mi], bq[ni], acc[mi][ni], 0, 0, 0);
        }
    }

    // exp in-register (reused for both row- and col-sums)
    #pragma unroll
    for (int mi = 0; mi < 4; ++mi)
        #pragma unroll
        for (int ni = 0; ni < 4; ++ni)
            #pragma unroll
            for (int q = 0; q < 4; ++q)
                acc[mi][ni][q] = __expf(10.0f * acc[mi][ni][q]);

    // ---- row-sums: C/D row = (lane>>4)*4 + q (+mi*16), col = lane&15 (+ni*16)
    {
        float rs[4][4];
        #pragma unroll
        for (int mi = 0; mi < 4; ++mi)
            #pragma unroll
            for (int q = 0; q < 4; ++q) {
                float s = 0.f;
                #pragma unroll
                for (int ni = 0; ni < 4; ++ni) s += acc[mi][ni][q];
                rs[mi][q] = s;
            }
        #pragma unroll
        for (int off = 1; off < 16; off <<= 1)
            #pragma unroll
            for (int mi = 0; mi < 4; ++mi)
                #pragma unroll
                for (int q = 0; q < 4; ++q)
                    rs[mi][q] += __shfl_xor(rs[mi][q], off, 64);

        if ((lane & 15) == 0) {
            float* St = S + ((ct < BIJ / 128) ? 0 : SIZE);
            int rq = (lane >> 4) * 4;
            #pragma unroll
            for (int mi = 0; mi < 4; ++mi)
                #pragma unroll
                for (int q = 0; q < 4; ++q)
                    atomicAdd(&St[rowA0 + wr*64 + mi*16 + rq + q], rs[mi][q]);
        }
    }

    // ---- col-sums (transpose contribution), off-diagonal tiles only
    if (rt != ct) {
        float cs[4];
        #pragma unroll
        for (int ni = 0; ni < 4; ++ni) {
            float s = 0.f;
            #pragma unroll
            for (int mi = 0; mi < 4; ++mi)
                #pragma unroll
                for (int q = 0; q < 4; ++q) s += acc[mi][ni][q];
            cs[ni] = s;
        }
        #pragma unroll
        for (int off = 16; off < 64; off <<= 1)
            #pragma unroll
            for (int ni = 0; ni < 4; ++ni)
                cs[ni] += __shfl_xor(cs[ni], off, 64);

        if (lane < 16) {
            float* St = S + ((rt < BIJ / 128) ? 0 : SIZE);
            #pragma unroll
            for (int ni = 0; ni < 4; ++ni)
                atomicAdd(&St[colB0 + wc*64 + ni*16 + lane], cs[ni]);
        }
    }
}

__global__ void zero_kernel(float* __restrict__ p, int n) {
    int i = blockIdx.x * 256 + threadIdx.x;
    if (i < n) p[i] = 0.f;
}

// Single block: per-row loss terms, total, write scalar.
__global__ __launch_bounds__(256) void loss_kernel(
    const float* __restrict__ S, const float* __restrict__ dii,
    float* __restrict__ out)
{
    __shared__ float red[4];
    float local = 0.f;
    const float c1 = logf((float)(BIJ - 1));
    const float c2 = logf((float)(BHALF - 1));
    for (int r = threadIdx.x; r < SIZE; r += 256) {
        float s1 = S[r], s2 = S[SIZE + r];
        float eii = __expf(10.0f * dii[r]);
        float denom = s1 + s2 - eii;
        float num, c;
        if (r < BIJ) { num = s1 - eii; c = c1; }
        else         { num = s2 - eii; c = c2; }
        local += logf(denom) - logf(num) + c;
    }
    float tot = block_reduce_sum(local, red);
    if (threadIdx.x == 0) out[0] = tot / (float)SIZE;
}

extern "C" void kernel_launch(void* const* d_in, const int* in_sizes, int n_in,
                              void* d_out, int out_size, void* d_ws, size_t ws_size,
                              hipStream_t stream) {
    const float* ei = (const float*)d_in[0];
    const float* ej = (const float*)d_in[1];
    const float* ek = (const float*)d_in[2];
    float* out = (float*)d_out;

    char* ws = (char*)d_ws;
    unsigned short* zb = (unsigned short*)ws;                    // 6144*2048*2 = 25165824 B
    float* dii = (float*)(ws + 25165824);                        // 24576 B
    float* S   = (float*)(ws + 25165824 + 24576);                // 2*6144*4 = 49152 B

    zero_kernel<<<dim3(48), dim3(256), 0, stream>>>(S, 2 * SIZE);
    normalize_kernel<<<dim3(SIZE), dim3(256), 0, stream>>>(ei, ej, ek, zb, dii);
    simexp_kernel<<<dim3(NT * (NT + 1) / 2), dim3(256), 0, stream>>>(zb, S);
    loss_kernel<<<dim3(1), dim3(256), 0, stream>>>(S, dii, out);
}